// Round 11
// baseline (114.051 us; speedup 1.0000x reference)
//
#include <hip/hip_runtime.h>
#include <math.h>

#define N_BOX 4096
#define B_IMG 16
#define MAXDET 100
#define MINSZ 25.0f
#define IOUT 0.3f
#define IG 16            // i-groups of 256 per image
#define JG 8             // j-groups of 512 per image
#define JW (N_BOX / JG)  // 512

// IoU with the reference's exact op order:
//   inter / (((ai + aj) - inter) + 1e-9)
// fp contract OFF so hipcc doesn't fuse wx*wy into the subtract (XLA doesn't).
__device__ __forceinline__ float iou_f(float ax1, float ay1, float ax2, float ay2, float aarea,
                                       float bx1, float by1, float bx2, float by2, float barea) {
#pragma clang fp contract(off)
    float lx = fmaxf(ax1, bx1);
    float ly = fmaxf(ay1, by1);
    float rx = fminf(ax2, bx2);
    float ry = fminf(ay2, by2);
    float wx = fmaxf(rx - lx, 0.0f);
    float wy = fmaxf(ry - ly, 0.0f);
    float inter = wx * wy;
    float denom = ((aarea + barea) - inter) + 1e-9f;
    return inter / denom;
}

// --- Kernel A: packed sort keys ---
// u = order-preserving uint of (valid ? score : -inf)  (no NaN / -0 in this data)
// C = (u << 12) | (4095 - i)  =>  stable-descending comparator == single u64 '>'
__global__ __launch_bounds__(256) void key_kernel(
        const float4* __restrict__ boxes, const float* __restrict__ scores,
        unsigned long long* __restrict__ ckey) {
    int idx = blockIdx.x * 256 + threadIdx.x;   // b*N + i
    float4 bx = boxes[idx];
    bool valid = ((bx.z - bx.x) >= MINSZ) && ((bx.w - bx.y) >= MINSZ);
    float k = valid ? scores[idx] : -INFINITY;
    unsigned u = __float_as_uint(k);
    u = (u & 0x80000000u) ? ~u : (u | 0x80000000u);
    int i = idx & (N_BOX - 1);
    ckey[idx] = ((unsigned long long)u << 12) | (unsigned long long)(N_BOX - 1 - i);
}

// --- Kernel B: partial stable ranks, 1 u64 compare per element ---
// grid: B_IMG*IG*JG = 2048 blocks x 256 threads -> 8 blocks/CU, 32 waves/CU.
// Scan address is block-uniform -> scalar SMEM loads + v_cmp_lt_u64 (VGPR=8).
__global__ __launch_bounds__(256) void partial_rank_kernel(
        const unsigned long long* __restrict__ ckey, unsigned short* __restrict__ part) {
    int blk = blockIdx.x;
    int jg = blk & (JG - 1);
    int ig = (blk >> 3) & (IG - 1);
    int b  = blk >> 7;                 // JG*IG = 128 blocks per image
    int t = threadIdx.x;
    int i = ig * 256 + t;
    unsigned long long ci = ckey[b * N_BOX + i];
    const unsigned long long* cj = ckey + b * N_BOX + jg * JW;  // wave-uniform scan
    int r = 0;
#pragma unroll 8
    for (int j = 0; j < JW; ++j)
        r += (cj[j] > ci) ? 1 : 0;
    part[(b * JG + jg) * N_BOX + i] = (unsigned short)r;
}

// --- Kernel C: fused scatter + 4-wave pull-based greedy NMS, one block/image ---
// Phase 0: block builds its image's inverse permutation in LDS (rank -> index)
// by summing the 8 partial ranks per box. Then the proven 4-wave NMS:
// per group of 4 chunks (64 boxes each): all waves pull vs finalized kept
// [0..K0) in parallel; then 4 barrier-separated serial intervals (delta-pull +
// intra-wave ballot greedy, ascending bit order = exact greedy order).
__global__ __launch_bounds__(256) void nms_kernel(
        const float4* __restrict__ boxes, const unsigned long long* __restrict__ ckey,
        const unsigned short* __restrict__ part, float* __restrict__ out) {
    __shared__ unsigned short sinv[N_BOX];       // 8 KiB: rank -> (i | valid<<15)
    __shared__ __align__(16) float4 kbox[384];   // kept boxes, rank order (max 99+256)
    __shared__ int scnt[4];                      // per-interval kept increments
    int b = blockIdx.x;
    int t = threadIdx.x;
    int w = t >> 6, l = t & 63;
    const float4* bb = boxes + (size_t)b * N_BOX;

    // Phase 0: scatter (ranks of all 4096 boxes of this image)
#pragma unroll
    for (int p = 0; p < 16; ++p) {
        int i = t + 256 * p;
        int rank = 0;
#pragma unroll
        for (int jg = 0; jg < JG; ++jg)
            rank += part[(b * JG + jg) * N_BOX + i];
        unsigned valid = (unsigned)(ckey[b * N_BOX + i] >> 43) & 1u;  // bit31 of u
        sinv[rank] = (unsigned short)(i | (valid << 15));
    }
    __syncthreads();

    int kept = 0;                                // block-uniform at group boundaries
    for (int g = 0; g < 16; ++g) {
        int c = g * 4 + w;                       // this wave's chunk
        unsigned short e = sinv[c * 64 + l];
        float4 bx = bb[e & 0xFFFu];
        float x1 = bx.x, y1 = bx.y, x2 = bx.z, y2 = bx.w;
        float ar;
        {
#pragma clang fp contract(off)
            ar = (x2 - x1) * (y2 - y1);
        }
        bool alive = (e >> 15) != 0;
        int K0 = kept;
        // phase 1 (parallel across 4 waves): pull vs finalized kept [0..K0)
        for (int q = 0; q < K0; ++q) {
            float4 kb = kbox[q];                 // uniform-addr broadcast read
            float kar;
            {
#pragma clang fp contract(off)
                kar = (kb.z - kb.x) * (kb.w - kb.y);
            }
            float v = iou_f(kb.x, kb.y, kb.z, kb.w, kar, x1, y1, x2, y2, ar);
            if (v > IOUT) alive = false;
        }
        // phase 2: serial resolve intervals
        for (int s = 0; s < 4; ++s) {
            if (w == s) {
                int Kcur = K0;
                for (int ss = 0; ss < s; ++ss) Kcur += scnt[ss];  // written in earlier intervals
                int cnt = 0;
                if (Kcur < MAXDET) {
                    // delta pull vs kept appended this group [K0..Kcur)
                    for (int q = K0; q < Kcur; ++q) {
                        float4 kb = kbox[q];
                        float kar;
                        {
#pragma clang fp contract(off)
                            kar = (kb.z - kb.x) * (kb.w - kb.y);
                        }
                        float v = iou_f(kb.x, kb.y, kb.z, kb.w, kar, x1, y1, x2, y2, ar);
                        if (v > IOUT) alive = false;
                    }
                    // intra-chunk greedy over surviving bits (ascending = greedy order)
                    unsigned long long m = __ballot(alive);
                    unsigned long long mm = m;
                    while (mm) {
                        int i = __ffsll(mm) - 1;
                        float bx1 = __shfl(x1, i), by1 = __shfl(y1, i);
                        float bx2 = __shfl(x2, i), by2 = __shfl(y2, i);
                        float ba  = __shfl(ar, i);
                        float v = iou_f(bx1, by1, bx2, by2, ba, x1, y1, x2, y2, ar);
                        bool sup = (l > i) && (v > IOUT) && ((m >> l) & 1ull);
                        unsigned long long sm = __ballot(sup);
                        m &= ~sm;
                        mm &= ~(1ull << i);
                        mm &= m;
                    }
                    cnt = __popcll(m);
                    int pos = Kcur + __popcll(m & ((1ull << l) - 1ull));
                    if ((m >> l) & 1ull) kbox[pos] = make_float4(x1, y1, x2, y2);
                }
                if (l == 0) scnt[s] = cnt;
            }
            __syncthreads();                     // publish kbox appends + scnt[s]
        }
        kept = K0 + scnt[0] + scnt[1] + scnt[2] + scnt[3];
        __syncthreads();                         // protect scnt reads from next group's writes
        if (kept >= MAXDET) break;               // uniform; kept list prefix-exact
    }

    int tot = kept < MAXDET ? kept : MAXDET;
    float* ob = out + (size_t)b * MAXDET * 5;
    for (int r = t; r < MAXDET; r += 256) {
        float* row = ob + r * 5;
        if (r < tot) {
            float4 kb = kbox[r];
            row[0] = (float)b;
            row[1] = kb.x; row[2] = kb.y; row[3] = kb.z; row[4] = kb.w;
        } else {
            row[0] = -1.0f;
            row[1] = 0.0f; row[2] = 0.0f; row[3] = 0.0f; row[4] = 0.0f;
        }
    }
}

extern "C" void kernel_launch(void* const* d_in, const int* in_sizes, int n_in,
                              void* d_out, int out_size, void* d_ws, size_t ws_size,
                              hipStream_t stream) {
    const float4* boxes = (const float4*)d_in[0];  // [16,4096,4] f32
    const float* scores = (const float*)d_in[1];   // [16,4096] f32
    float* out = (float*)d_out;                    // [16,100,5] f32

    // ws layout (1.5 MiB): ckey u64 [0, 512K) | part u16 [512K, 1536K)
    unsigned long long* ckey = (unsigned long long*)d_ws;
    unsigned short* part     = (unsigned short*)((char*)d_ws + (size_t)524288);

    key_kernel<<<B_IMG * N_BOX / 256, 256, 0, stream>>>(boxes, scores, ckey);
    partial_rank_kernel<<<B_IMG * IG * JG, 256, 0, stream>>>(ckey, part);
    nms_kernel<<<B_IMG, 256, 0, stream>>>(boxes, ckey, part, out);
}

// Round 12
// 103.140 us; speedup vs baseline: 1.1058x; 1.1058x over previous
//
#include <hip/hip_runtime.h>
#include <math.h>

#define N_BOX 4096
#define B_IMG 16
#define MAXDET 100
#define MINSZ 25.0f
#define IOUT 0.3f
#define NBUCK 1024

// IoU with the reference's exact op order:
//   inter / (((ai + aj) - inter) + 1e-9)
// fp contract OFF so hipcc doesn't fuse wx*wy into the subtract (XLA doesn't).
__device__ __forceinline__ float iou_f(float ax1, float ay1, float ax2, float ay2, float aarea,
                                       float bx1, float by1, float bx2, float by2, float barea) {
#pragma clang fp contract(off)
    float lx = fmaxf(ax1, bx1);
    float ly = fmaxf(ay1, by1);
    float rx = fminf(ax2, bx2);
    float ry = fminf(ay2, by2);
    float wx = fmaxf(rx - lx, 0.0f);
    float wy = fmaxf(ry - ly, 0.0f);
    float inter = wx * wy;
    float denom = ((aarea + barea) - inter) + 1e-9f;
    return inter / denom;
}

// ONE kernel per image (16 blocks x 256 threads):
//  Phase S (sort): packed unique key C = (orderU32(score)<<12)|(4095-i); bucket
//  by min(1023,int(score*1024)) (monotone), histogram -> suffix-scan ->
//  atomic scatter -> within-bucket exact u64 rank (avg ~3 compares). Invalid
//  boxes ranked after all valid, in index order, via ballot chunk prefixes.
//  Unique keys => any sort == the reference's stable argsort exactly.
//  Phase N (NMS): proven 4-wave pull-based greedy (exact).
__global__ __launch_bounds__(256) void fused_kernel(
        const float4* __restrict__ boxes, const float* __restrict__ scores,
        float* __restrict__ out) {
    __shared__ __align__(16) unsigned long long bkey[N_BOX];  // 32 KiB bucket-sorted keys
    __shared__ unsigned short sinv[N_BOX];                    // 8 KiB rank -> (i | valid<<15)
    __shared__ int cnt[NBUCK];                                // 4 KiB
    __shared__ int start[NBUCK];                              // 4 KiB (suffix sums, then cursors)
    __shared__ int chunkInv[64];                              // invalid count per 64-chunk
    __shared__ int chunkPre[64];                              // exclusive prefix of chunkInv
    __shared__ int scratch[256];                              // 1 KiB scan scratch
    __shared__ int wsum[4];
    __shared__ int nvalidS;
    __shared__ __align__(16) float4 kbox[384];                // kept boxes (max 99+256)
    __shared__ int scnt[4];

    int b = blockIdx.x;
    int t = threadIdx.x;
    int w = t >> 6, l = t & 63;
    const float4* bb = boxes + (size_t)b * N_BOX;
    const float* ss = scores + (size_t)b * N_BOX;

    for (int q = t; q < NBUCK; q += 256) cnt[q] = 0;
    __syncthreads();

    // --- pass 1: keys, validity, histogram, per-chunk invalid ballots ---
    unsigned long long key[16];
    int buck[16];
    unsigned char ipre[16];
    unsigned vmask = 0;
#pragma unroll
    for (int p = 0; p < 16; ++p) {
        int i = w * 64 + 256 * p + l;             // lanes of (w,p) cover 64 consecutive i
        float4 bx = bb[i];
        float sc = ss[i];
        bool valid = ((bx.z - bx.x) >= MINSZ) && ((bx.w - bx.y) >= MINSZ);
        float k = valid ? sc : -INFINITY;
        unsigned u = __float_as_uint(k);
        u = (u & 0x80000000u) ? ~u : (u | 0x80000000u);
        key[p] = ((unsigned long long)u << 12) | (unsigned long long)(N_BOX - 1 - i);
        unsigned long long im = __ballot(!valid);
        ipre[p] = (unsigned char)__popcll(im & ((1ull << l) - 1ull));
        if (l == 0) chunkInv[w + 4 * p] = __popcll(im);
        if (valid) {
            vmask |= (1u << p);
            int bk = (int)(sc * 1024.0f);         // monotone bucketing
            bk = bk < 0 ? 0 : (bk > NBUCK - 1 ? NBUCK - 1 : bk);
            buck[p] = bk;
            atomicAdd(&cnt[bk], 1);
        }
    }
    __syncthreads();

    // --- chunk prefix (exclusive) over 64 chunks; total invalid -> nvalid ---
    if (t < 64) {
        int v = chunkInv[t];
        int x = v;
        for (int off = 1; off < 64; off <<= 1) {
            int y = __shfl_up(x, off);
            if (l >= off) x += y;
        }
        chunkPre[t] = x - v;
        if (t == 63) nvalidS = N_BOX - x;
    }
    __syncthreads();

    // --- bucket suffix-sum: start[bk] = sum_{bk' > bk} cnt[bk'] ---
    // thread t owns buckets [4t, 4t+4); reverse-stage, ascending excl scan, back.
    int S = 0;
#pragma unroll
    for (int q = 0; q < 4; ++q) S += cnt[t * 4 + q];
    scratch[255 - t] = S;
    __syncthreads();
    int xv = scratch[t];
    int incl = xv;
    for (int off = 1; off < 64; off <<= 1) {
        int y = __shfl_up(incl, off);
        if (l >= off) incl += y;
    }
    if (l == 63) wsum[w] = incl;
    __syncthreads();
    int woff = 0;
    for (int q = 0; q < w; ++q) woff += wsum[q];
    int excl = woff + incl - xv;                  // exclusive prefix at index t
    __syncthreads();                              // all xv reads done
    scratch[t] = excl;
    __syncthreads();
    int T = scratch[255 - t];                     // sum over threads u' > t of S_u'
    int running = T;
#pragma unroll
    for (int q = 3; q >= 0; --q) {
        start[t * 4 + q] = running;
        running += cnt[t * 4 + q];
    }
    __syncthreads();

    // --- scatter valid keys (start[] doubles as cursor; final value = seg end) ---
#pragma unroll
    for (int p = 0; p < 16; ++p) {
        if (vmask & (1u << p)) {
            int ps = atomicAdd(&start[buck[p]], 1);
            bkey[ps] = key[p];
        }
    }
    __syncthreads();

    // --- exact ranks -> sinv permutation ---
    int nvalid = nvalidS;
#pragma unroll
    for (int p = 0; p < 16; ++p) {
        int i = w * 64 + 256 * p + l;
        int r;
        unsigned vbit = (vmask >> p) & 1u;
        if (vbit) {
            int bk = buck[p];
            int end = start[bk];
            int beg = end - cnt[bk];
            unsigned long long mk = key[p];
            r = beg;
            for (int q = beg; q < end; ++q)
                r += (bkey[q] > mk) ? 1 : 0;      // unique keys: exact stable order
        } else {
            r = nvalid + chunkPre[w + 4 * p] + (int)ipre[p];
        }
        sinv[r] = (unsigned short)(i | (vbit << 15));
    }
    __syncthreads();

    // --- 4-wave pull-based greedy NMS (exact; proven) ---
    int kept = 0;
    for (int g = 0; g < 16; ++g) {
        int c = g * 4 + w;
        unsigned short e = sinv[c * 64 + l];
        float4 bx = bb[e & 0xFFFu];
        float x1 = bx.x, y1 = bx.y, x2 = bx.z, y2 = bx.w;
        float ar;
        {
#pragma clang fp contract(off)
            ar = (x2 - x1) * (y2 - y1);
        }
        bool alive = (e >> 15) != 0;
        int K0 = kept;
        for (int q = 0; q < K0; ++q) {
            float4 kb = kbox[q];
            float kar;
            {
#pragma clang fp contract(off)
                kar = (kb.z - kb.x) * (kb.w - kb.y);
            }
            float v = iou_f(kb.x, kb.y, kb.z, kb.w, kar, x1, y1, x2, y2, ar);
            if (v > IOUT) alive = false;
        }
        for (int s = 0; s < 4; ++s) {
            if (w == s) {
                int Kcur = K0;
                for (int ss2 = 0; ss2 < s; ++ss2) Kcur += scnt[ss2];
                int cnt2 = 0;
                if (Kcur < MAXDET) {
                    for (int q = K0; q < Kcur; ++q) {
                        float4 kb = kbox[q];
                        float kar;
                        {
#pragma clang fp contract(off)
                            kar = (kb.z - kb.x) * (kb.w - kb.y);
                        }
                        float v = iou_f(kb.x, kb.y, kb.z, kb.w, kar, x1, y1, x2, y2, ar);
                        if (v > IOUT) alive = false;
                    }
                    unsigned long long m = __ballot(alive);
                    unsigned long long mm = m;
                    while (mm) {
                        int i = __ffsll(mm) - 1;
                        float bx1 = __shfl(x1, i), by1 = __shfl(y1, i);
                        float bx2 = __shfl(x2, i), by2 = __shfl(y2, i);
                        float ba  = __shfl(ar, i);
                        float v = iou_f(bx1, by1, bx2, by2, ba, x1, y1, x2, y2, ar);
                        bool sup = (l > i) && (v > IOUT) && ((m >> l) & 1ull);
                        unsigned long long sm = __ballot(sup);
                        m &= ~sm;
                        mm &= ~(1ull << i);
                        mm &= m;
                    }
                    cnt2 = __popcll(m);
                    int pos = Kcur + __popcll(m & ((1ull << l) - 1ull));
                    if ((m >> l) & 1ull) kbox[pos] = make_float4(x1, y1, x2, y2);
                }
                if (l == 0) scnt[s] = cnt2;
            }
            __syncthreads();
        }
        kept = K0 + scnt[0] + scnt[1] + scnt[2] + scnt[3];
        __syncthreads();
        if (kept >= MAXDET) break;
    }

    int tot = kept < MAXDET ? kept : MAXDET;
    float* ob = out + (size_t)b * MAXDET * 5;
    for (int r = t; r < MAXDET; r += 256) {
        float* row = ob + r * 5;
        if (r < tot) {
            float4 kb = kbox[r];
            row[0] = (float)b;
            row[1] = kb.x; row[2] = kb.y; row[3] = kb.z; row[4] = kb.w;
        } else {
            row[0] = -1.0f;
            row[1] = 0.0f; row[2] = 0.0f; row[3] = 0.0f; row[4] = 0.0f;
        }
    }
}

extern "C" void kernel_launch(void* const* d_in, const int* in_sizes, int n_in,
                              void* d_out, int out_size, void* d_ws, size_t ws_size,
                              hipStream_t stream) {
    const float4* boxes = (const float4*)d_in[0];  // [16,4096,4] f32
    const float* scores = (const float*)d_in[1];   // [16,4096] f32
    float* out = (float*)d_out;                    // [16,100,5] f32
    (void)d_ws; (void)ws_size;

    fused_kernel<<<B_IMG, 256, 0, stream>>>(boxes, scores, out);
}

// Round 16
// 91.539 us; speedup vs baseline: 1.2459x; 1.1267x over previous
//
#include <hip/hip_runtime.h>
#include <math.h>

#define N_BOX 4096
#define B_IMG 16
#define MAXDET 100
#define MINSZ 25.0f
#define NBUCK 1024
#define NW 8     // waves per block
#define NT 512   // threads per block

// Exact IEEE-equivalent of  RN_f32(inter/denom) > 0.3f  for denom > 0:
// c = 0.3f = 0x1.333334p-2 (even mantissa); next-up u = 0x1.333336p-2;
// midpoint m = 0x1.333335p-2. RN(x) > c <=> x > m (tie x=m rounds to c).
// x = inter/denom (real) > m <=> inter > m*denom; in f64 both sides exact
// (inter: 48 bits; m*denom: 25+24=49 bits <= 53). Division eliminated.
__device__ __forceinline__ bool sup_test(float ax1, float ay1, float ax2, float ay2, float aarea,
                                         float bx1, float by1, float bx2, float by2, float barea) {
#pragma clang fp contract(off)
    float lx = fmaxf(ax1, bx1);
    float ly = fmaxf(ay1, by1);
    float rx = fminf(ax2, bx2);
    float ry = fminf(ay2, by2);
    float wx = fmaxf(rx - lx, 0.0f);
    float wy = fmaxf(ry - ly, 0.0f);
    float inter = wx * wy;
    float denom = ((aarea + barea) - inter) + 1e-9f;
    const double M = 0x1.333335p-2;
    return (double)inter > M * (double)denom;
}

// ONE kernel per image (16 blocks x 512 threads):
//  Sort: packed unique key C = (orderU32(score)<<12)|(4095-i); bucket by
//  min(1023,int(score*1024)) (monotone); histogram -> suffix-scan -> atomic
//  scatter -> within-bucket exact u64 rank. Invalid boxes ranked after all
//  valid in index order via ballot chunk prefixes. Unique keys => exactly the
//  reference's stable argsort.  NMS: 8-wave pull-based greedy (exact).
__global__ __launch_bounds__(NT) void fused_kernel(
        const float4* __restrict__ boxes, const float* __restrict__ scores,
        float* __restrict__ out) {
    __shared__ __align__(16) unsigned long long bkey[N_BOX];  // 32 KiB
    __shared__ unsigned short sinv[N_BOX];                    // 8 KiB
    __shared__ int cnt[NBUCK];                                // 4 KiB
    __shared__ int start[NBUCK];                              // 4 KiB
    __shared__ int chunkInv[64];
    __shared__ int chunkPre[64];
    __shared__ int scratch[NT];                               // 2 KiB
    __shared__ int wsum[NW];
    __shared__ int nvalidS;
    __shared__ __align__(16) float4 kbox[192];                // kept (max 99+64=163)
    __shared__ float kar[192];                                // kept areas
    __shared__ int scnt[NW];

    int b = blockIdx.x;
    int t = threadIdx.x;
    int w = t >> 6, l = t & 63;
    const float4* bb = boxes + (size_t)b * N_BOX;
    const float* ss = scores + (size_t)b * N_BOX;

    for (int q = t; q < NBUCK; q += NT) cnt[q] = 0;
    __syncthreads();

    // --- pass 1: keys, validity, histogram, per-chunk invalid ballots ---
    unsigned long long key[8];
    int buck[8];
    unsigned char ipre[8];
    unsigned vmask = 0;
#pragma unroll
    for (int p = 0; p < 8; ++p) {
        int i = w * 64 + NT * p + l;              // chunk(i) = w + 8p
        float4 bx = bb[i];
        float sc = ss[i];
        bool valid = ((bx.z - bx.x) >= MINSZ) && ((bx.w - bx.y) >= MINSZ);
        float k = valid ? sc : -INFINITY;
        unsigned u = __float_as_uint(k);
        u = (u & 0x80000000u) ? ~u : (u | 0x80000000u);
        key[p] = ((unsigned long long)u << 12) | (unsigned long long)(N_BOX - 1 - i);
        unsigned long long im = __ballot(!valid);
        ipre[p] = (unsigned char)__popcll(im & ((1ull << l) - 1ull));
        if (l == 0) chunkInv[w + NW * p] = __popcll(im);
        if (valid) {
            vmask |= (1u << p);
            int bk = (int)(sc * 1024.0f);         // monotone bucketing
            bk = bk < 0 ? 0 : (bk > NBUCK - 1 ? NBUCK - 1 : bk);
            buck[p] = bk;
            atomicAdd(&cnt[bk], 1);
        }
    }
    __syncthreads();

    // --- exclusive prefix over the 64 chunks' invalid counts (wave 0) ---
    if (t < 64) {
        int v = chunkInv[t];
        int x = v;
        for (int off = 1; off < 64; off <<= 1) {
            int y = __shfl_up(x, off);
            if (l >= off) x += y;
        }
        chunkPre[t] = x - v;
        if (t == 63) nvalidS = N_BOX - x;
    }
    __syncthreads();

    // --- bucket suffix-sum: start[bk] = sum_{bk' > bk} cnt[bk'] (2 buckets/thread) ---
    int S = cnt[2 * t] + cnt[2 * t + 1];
    scratch[NT - 1 - t] = S;
    __syncthreads();
    int xv = scratch[t];
    int incl = xv;
    for (int off = 1; off < 64; off <<= 1) {
        int y = __shfl_up(incl, off);
        if (l >= off) incl += y;
    }
    if (l == 63) wsum[w] = incl;
    __syncthreads();
    int woff = 0;
    for (int q = 0; q < w; ++q) woff += wsum[q];
    int excl = woff + incl - xv;
    __syncthreads();
    scratch[t] = excl;
    __syncthreads();
    int T = scratch[NT - 1 - t];                  // sum of S over threads > t
    start[2 * t + 1] = T;                         // buckets above 2t+1
    start[2 * t] = T + cnt[2 * t + 1];            // buckets above 2t
    __syncthreads();

    // --- scatter valid keys (start[] doubles as cursor; final value = seg end) ---
#pragma unroll
    for (int p = 0; p < 8; ++p) {
        if (vmask & (1u << p)) {
            int ps = atomicAdd(&start[buck[p]], 1);
            bkey[ps] = key[p];
        }
    }
    __syncthreads();

    // --- exact ranks -> sinv permutation ---
    int nvalid = nvalidS;
#pragma unroll
    for (int p = 0; p < 8; ++p) {
        int i = w * 64 + NT * p + l;
        int r;
        unsigned vbit = (vmask >> p) & 1u;
        if (vbit) {
            int bk = buck[p];
            int end = start[bk];
            int beg = end - cnt[bk];
            unsigned long long mk = key[p];
            r = beg;
            for (int q = beg; q < end; ++q)
                r += (bkey[q] > mk) ? 1 : 0;      // unique keys: exact stable order
        } else {
            r = nvalid + chunkPre[w + NW * p] + (int)ipre[p];
        }
        sinv[r] = (unsigned short)(i | (vbit << 15));
    }
    __syncthreads();

    // --- 8-wave pull-based greedy NMS (exact; proven structure) ---
    int kept = 0;
    for (int g = 0; g < 8; ++g) {
        int c = g * NW + w;
        unsigned short e = sinv[c * 64 + l];
        float4 bx = bb[e & 0xFFFu];
        float x1 = bx.x, y1 = bx.y, x2 = bx.z, y2 = bx.w;
        float ar;
        {
#pragma clang fp contract(off)
            ar = (x2 - x1) * (y2 - y1);
        }
        bool alive = (e >> 15) != 0;
        int K0 = kept;
        // phase 1 (parallel across 8 waves): pull vs finalized kept [0..K0)
        for (int q = 0; q < K0; ++q) {
            float4 kb = kbox[q];
            if (sup_test(kb.x, kb.y, kb.z, kb.w, kar[q], x1, y1, x2, y2, ar))
                alive = false;
        }
        // phase 2: serial resolve intervals
        for (int s = 0; s < NW; ++s) {
            if (w == s) {
                int Kcur = K0;
                for (int ss2 = 0; ss2 < s; ++ss2) Kcur += scnt[ss2];
                int cnt2 = 0;
                if (Kcur < MAXDET) {
                    for (int q = K0; q < Kcur; ++q) {
                        float4 kb = kbox[q];
                        if (sup_test(kb.x, kb.y, kb.z, kb.w, kar[q], x1, y1, x2, y2, ar))
                            alive = false;
                    }
                    unsigned long long m = __ballot(alive);
                    unsigned long long mm = m;
                    while (mm) {
                        int i = __ffsll(mm) - 1;
                        float bx1 = __shfl(x1, i), by1 = __shfl(y1, i);
                        float bx2 = __shfl(x2, i), by2 = __shfl(y2, i);
                        float ba  = __shfl(ar, i);
                        bool sup = (l > i) && ((m >> l) & 1ull) &&
                                   sup_test(bx1, by1, bx2, by2, ba, x1, y1, x2, y2, ar);
                        unsigned long long sm = __ballot(sup);
                        m &= ~sm;
                        mm &= ~(1ull << i);
                        mm &= m;
                    }
                    cnt2 = __popcll(m);
                    int pos = Kcur + __popcll(m & ((1ull << l) - 1ull));
                    if ((m >> l) & 1ull) {
                        kbox[pos] = make_float4(x1, y1, x2, y2);
                        kar[pos] = ar;
                    }
                }
                if (l == 0) scnt[s] = cnt2;
            }
            __syncthreads();                      // publish kbox/kar appends + scnt[s]
        }
        int knew = K0;
        for (int q = 0; q < NW; ++q) knew += scnt[q];
        kept = knew;
        __syncthreads();                          // protect scnt reads from next group
        if (kept >= MAXDET) break;                // uniform
    }

    int tot = kept < MAXDET ? kept : MAXDET;
    float* ob = out + (size_t)b * MAXDET * 5;
    for (int r = t; r < MAXDET; r += NT) {
        float* row = ob + r * 5;
        if (r < tot) {
            float4 kb = kbox[r];
            row[0] = (float)b;
            row[1] = kb.x; row[2] = kb.y; row[3] = kb.z; row[4] = kb.w;
        } else {
            row[0] = -1.0f;
            row[1] = 0.0f; row[2] = 0.0f; row[3] = 0.0f; row[4] = 0.0f;
        }
    }
}

extern "C" void kernel_launch(void* const* d_in, const int* in_sizes, int n_in,
                              void* d_out, int out_size, void* d_ws, size_t ws_size,
                              hipStream_t stream) {
    const float4* boxes = (const float4*)d_in[0];  // [16,4096,4] f32
    const float* scores = (const float*)d_in[1];   // [16,4096] f32
    float* out = (float*)d_out;                    // [16,100,5] f32
    (void)d_ws; (void)ws_size;

    fused_kernel<<<B_IMG, NT, 0, stream>>>(boxes, scores, out);
}